// Round 17
// baseline (7565.816 us; speedup 1.0000x reference)
//
#include <hip/hip_runtime.h>

#define T_ 1024
#define S_ 1024
#define H_ 2048
#define A_ 128
#define NBLK 256
#define THR 256

typedef __attribute__((ext_vector_type(8))) short short8;
typedef __attribute__((ext_vector_type(4))) float f32x4;

__device__ __forceinline__ float sigmf(float v) { return 1.0f / (1.0f + __expf(-v)); }

__device__ __forceinline__ ushort f2bf(float f) {
    uint u = __float_as_uint(f);
    return (ushort)((u + 0x7fffu + ((u >> 16) & 1u)) >> 16);
}

__device__ __forceinline__ short8 pack8(const float* __restrict__ s) {
    const float4 f0 = *(const float4*)(s);
    const float4 f1 = *(const float4*)(s + 4);
    uint4 o;
    o.x = (uint)f2bf(f0.x) | ((uint)f2bf(f0.y) << 16);
    o.y = (uint)f2bf(f0.z) | ((uint)f2bf(f0.w) << 16);
    o.z = (uint)f2bf(f1.x) | ((uint)f2bf(f1.y) << 16);
    o.w = (uint)f2bf(f1.z) | ((uint)f2bf(f1.w) << 16);
    return __builtin_bit_cast(short8, o);
}

// verify preloaded tags; on mismatch, re-poll until all carry `tag`
__device__ __forceinline__ void verify8(const uint* __restrict__ p, uint tag, uint* g) {
    for (;;) {
        uint bad = 0;
#pragma unroll
        for (int i = 0; i < 8; ++i) bad |= (g[i] >> 16) ^ tag;
        if (bad == 0) return;
        __builtin_amdgcn_s_sleep(1);
#pragma unroll
        for (int i = 0; i < 8; ++i)
            g[i] = __hip_atomic_load(p + i, __ATOMIC_RELAXED, __HIP_MEMORY_SCOPE_AGENT);
    }
}

__device__ __forceinline__ void poll8(const uint* __restrict__ p, uint tag, uint* g) {
#pragma unroll
    for (int i = 0; i < 8; ++i)
        g[i] = __hip_atomic_load(p + i, __ATOMIC_RELAXED, __HIP_MEMORY_SCOPE_AGENT);
    verify8(p, tag, g);
}

__device__ __forceinline__ void pack_hc(const uint* g, ushort* dst) {
    uint4 o;
    o.x = (g[0] & 0xffffu) | (g[1] << 16); o.y = (g[2] & 0xffffu) | (g[3] << 16);
    o.z = (g[4] & 0xffffu) | (g[5] << 16); o.w = (g[6] & 0xffffu) | (g[7] << 16);
    *(uint4*)dst = o;
}

// ---------------- fp32 -> bf16 (RNE) packed conversion ----------------
__global__ void cvt_bf16(const float* __restrict__ src,
                         ushort* __restrict__ dst, int n4) {
    int i = blockIdx.x * blockDim.x + threadIdx.x;
    const int stride = gridDim.x * blockDim.x;
    for (; i < n4; i += stride) {
        const uint4 u = reinterpret_cast<const uint4*>(src)[i];
        ushort4 o;
        uint a;
        a = u.x; o.x = (ushort)((a + 0x7fffu + ((a >> 16) & 1u)) >> 16);
        a = u.y; o.y = (ushort)((a + 0x7fffu + ((a >> 16) & 1u)) >> 16);
        a = u.z; o.z = (ushort)((a + 0x7fffu + ((a >> 16) & 1u)) >> 16);
        a = u.w; o.w = (ushort)((a + 0x7fffu + ((a >> 16) & 1u)) >> 16);
        reinterpret_cast<ushort4*>(dst)[i] = o;
    }
}

// ---------------- X1 = x @ W_ih1^T + (b_ih1+b_hh1) : MFMA bf16 GEMM ----------------
__global__ __launch_bounds__(256, 2) void gemm_x1(
    const ushort* __restrict__ Abf, const ushort* __restrict__ Bbf,
    const float* __restrict__ bih1, const float* __restrict__ bhh1,
    float* __restrict__ X1) {
    __shared__ ushort At[64][80];
    __shared__ ushort Bt[64][80];
    const int tx = threadIdx.x;
    const int w = tx >> 6, lane = tx & 63;
    const int row0 = blockIdx.x * 64;
    const int col0 = blockIdx.y * 64;
    f32x4 acc[4];
#pragma unroll
    for (int n4 = 0; n4 < 4; ++n4) { acc[n4][0] = 0.f; acc[n4][1] = 0.f; acc[n4][2] = 0.f; acc[n4][3] = 0.f; }
    const int sr = tx >> 2, sc = (tx & 3) * 16;
    for (int k0 = 0; k0 < 1024; k0 += 64) {
        const uint4 a0 = *(const uint4*)(Abf + (size_t)(row0 + sr) * 1024 + k0 + sc);
        const uint4 a1 = *(const uint4*)(Abf + (size_t)(row0 + sr) * 1024 + k0 + sc + 8);
        const uint4 b0 = *(const uint4*)(Bbf + (size_t)(col0 + sr) * 1024 + k0 + sc);
        const uint4 b1 = *(const uint4*)(Bbf + (size_t)(col0 + sr) * 1024 + k0 + sc + 8);
        __syncthreads();
        *(uint4*)(&At[sr][sc]) = a0;
        *(uint4*)(&At[sr][sc + 8]) = a1;
        *(uint4*)(&Bt[sr][sc]) = b0;
        *(uint4*)(&Bt[sr][sc + 8]) = b1;
        __syncthreads();
#pragma unroll
        for (int kk = 0; kk < 64; kk += 32) {
            short8 af = *(const short8*)(&At[16 * w + (lane & 15)][kk + (lane >> 4) * 8]);
#pragma unroll
            for (int n4 = 0; n4 < 4; ++n4) {
                short8 bf = *(const short8*)(&Bt[n4 * 16 + (lane & 15)][kk + (lane >> 4) * 8]);
                acc[n4] = __builtin_amdgcn_mfma_f32_16x16x32_bf16(af, bf, acc[n4], 0, 0, 0);
            }
        }
    }
#pragma unroll
    for (int n4 = 0; n4 < 4; ++n4) {
        const int col = col0 + n4 * 16 + (lane & 15);
        const float bias = bih1[col] + bhh1[col];
#pragma unroll
        for (int r = 0; r < 4; ++r) {
            const int rowv = row0 + 16 * w + (lane >> 4) * 4 + r;
            X1[(size_t)rowv * 8192 + col] = acc[n4][r] + bias;
        }
    }
}

// ---------------- persistent LSTM: pipelined polls, AGPR-resident weights --------
// hp1/hp2: [2][256][16] u32 per-block 64B single-writer tagged lines.
// R17 = R16 with ONE change: the h2[t-2] load-issue is hoisted to the very
// top of the iteration (before the front verify), so its L3 round overlaps
// the front-verify spin instead of starting after it. Verify placement
// (after L1 MFMA) unchanged; correctness unaffected (stale loads re-poll).
__global__ __launch_bounds__(THR, 1) void lstm_mfma(
    const float* __restrict__ X1,
    const float* __restrict__ Whh1,
    const float* __restrict__ W2i, const float* __restrict__ W2h,
    const float* __restrict__ bih2, const float* __restrict__ bhh2,
    const float* __restrict__ Wlin, const float* __restrict__ blin,
    uint* __restrict__ hp1, uint* __restrict__ hp2,
    float* __restrict__ out)
{
    __shared__ ushort hc[4096];    // h1[t-1] (2048) || h2[t-2] (2048) bf16
    __shared__ float pl[4][64];    // per-wave K-partials (rows 0-31 L1, 32-63 L2)

    const int b = blockIdx.x, tid = threadIdx.x;
    const int w = tid >> 6, lane = tid & 63;
    const int j0 = b * 8;
    const int m = lane & 15;
    const int ko = (lane >> 4) * 8;

    // ---- prologue: weight fragments (MFMA A layout), fp32 -> bf16 ----
    short8 a1[2][16];
#pragma unroll
    for (int g = 0; g < 2; ++g) {
        const int r = g * 16 + m;
        const int R = (r & 3) * H_ + j0 + (r >> 2);
        const float* src = Whh1 + (size_t)R * H_ + w * 512 + ko;
#pragma unroll
        for (int c = 0; c < 16; ++c)
            a1[g][c] = pack8(src + c * 32);
    }
    short8 a2[2][32];
#pragma unroll
    for (int g = 0; g < 2; ++g) {
        const int r = g * 16 + m;
        const int R = (r & 3) * H_ + j0 + (r >> 2);
        const float* base = (w < 2) ? (W2i + (size_t)R * H_ + w * 1024 + ko)
                                    : (W2h + (size_t)R * H_ + (w - 2) * 1024 + ko);
#pragma unroll
        for (int c = 0; c < 32; ++c)
            a2[g][c] = pack8(base + c * 32);
    }

    float c1 = 0.f, c2 = 0.f;
    float b2g[4] = {0.f, 0.f, 0.f, 0.f};
    if (tid >= 8 && tid < 16) {
        const int jl = tid - 8;
#pragma unroll
        for (int g = 0; g < 4; ++g) {
            const int R = g * H_ + j0 + jl;
            b2g[g] = bih2[R] + bhh2[R];
        }
    }

    uint g0n[8];   // prefetched h1 line (carried across iterations)
#pragma unroll
    for (int i = 0; i < 8; ++i) g0n[i] = 0u;

#pragma unroll 1
    for (int t = 0; t <= T_; ++t) {
        // ---- issue BACK loads h2[t-2] FIRST (overlap with front verify) ----
        uint g1[8];
        if (t >= 2) {
            const uint* p2 = hp2 + ((((t - 2) & 1) * 256 + tid) << 4);
#pragma unroll
            for (int i = 0; i < 8; ++i)
                g1[i] = __hip_atomic_load(p2 + i, __ATOMIC_RELAXED, __HIP_MEMORY_SCOPE_AGENT);
        } else {
#pragma unroll
            for (int i = 0; i < 8; ++i) g1[i] = 0u;
        }

        // early per-thread X1 fetch (threads 0..7)
        float xg[4] = {0.f, 0.f, 0.f, 0.f};
        if (tid < 8 && t < T_) {
#pragma unroll
            for (int g = 0; g < 4; ++g)
                xg[g] = X1[(size_t)t * 8192 + g * H_ + j0 + tid];
        }

        // ---- FRONT: verify prefetched h1[t-1] (round hidden under loop-back) ----
        if (t >= 1) {
            const uint* p = hp1 + ((((t - 1) & 1) * 256 + tid) << 4);
            verify8(p, (uint)(t - 1) & 0xffffu, g0n);
        }
        pack_hc(g0n, hc + tid * 8);   // t==0: zeros; own-wave slice of the front half
        // (bar1 removed: L1 below reads only this wave's own staged slice)

        // ---- L1 MFMA over h1[t-1] (own-wave slice) ----
        if (t < T_) {
            f32x4 acc0, acc1;
#pragma unroll
            for (int r = 0; r < 4; ++r) { acc0[r] = 0.f; acc1[r] = 0.f; }
            const ushort* h1s = hc + w * 512;
#pragma unroll
            for (int c = 0; c < 16; ++c) {
                const short8 bfr = *(const short8*)(h1s + c * 32 + ko);
                acc0 = __builtin_amdgcn_mfma_f32_16x16x32_bf16(a1[0][c], bfr, acc0, 0, 0, 0);
                acc1 = __builtin_amdgcn_mfma_f32_16x16x32_bf16(a1[1][c], bfr, acc1, 0, 0, 0);
            }
            if (m == 0) {
                const int r4 = (lane >> 4) * 4;
#pragma unroll
                for (int r = 0; r < 4; ++r) {
                    pl[w][ 0 + r4 + r] = acc0[r];
                    pl[w][16 + r4 + r] = acc1[r];
                }
            }
        }

        // ---- BACK verify (round overlapped since iter top) + stage h2[t-2] ----
        if (t >= 2) {
            const uint* p2 = hp2 + ((((t - 2) & 1) * 256 + tid) << 4);
            verify8(p2, (uint)(t - 2) & 0xffffu, g1);
        }
        pack_hc(g1, hc + 2048 + tid * 8);   // disjoint from L1's hc reads
        __syncthreads();   // bar2: pl L1 + all staging (front+back) ready

        // ---- publish h1[t] (mid-iter) ----
        if (tid < 8 && t < T_) {
            float s[4];
#pragma unroll
            for (int g = 0; g < 4; ++g)
                s[g] = pl[0][tid * 4 + g] + pl[1][tid * 4 + g]
                     + pl[2][tid * 4 + g] + pl[3][tid * 4 + g];
            const float ig = sigmf(s[0] + xg[0]);
            const float fg = sigmf(s[1] + xg[1]);
            const float gv = tanhf(s[2] + xg[2]);
            const float og = sigmf(s[3] + xg[3]);
            c1 = fg * c1 + ig * gv;
            const float h1n = og * tanhf(c1);
            const uint pv = (((uint)t & 0xffffu) << 16) | (uint)f2bf(h1n);
            __hip_atomic_store(hp1 + (((t & 1) * 256 + b) << 4) + tid, pv,
                               __ATOMIC_RELAXED, __HIP_MEMORY_SCOPE_AGENT);
        }

        // ---- L2 MFMA over [h1[t-1]; h2[t-2]] ----
        if (t >= 1) {
            f32x4 acc2, acc3;
#pragma unroll
            for (int r = 0; r < 4; ++r) { acc2[r] = 0.f; acc3[r] = 0.f; }
            const ushort* hcs = hc + w * 1024;
#pragma unroll
            for (int c = 0; c < 32; ++c) {
                const short8 bfr = *(const short8*)(hcs + c * 32 + ko);
                acc2 = __builtin_amdgcn_mfma_f32_16x16x32_bf16(a2[0][c], bfr, acc2, 0, 0, 0);
                acc3 = __builtin_amdgcn_mfma_f32_16x16x32_bf16(a2[1][c], bfr, acc3, 0, 0, 0);
            }
            if (m == 0) {
                const int r4 = (lane >> 4) * 4;
#pragma unroll
                for (int r = 0; r < 4; ++r) {
                    pl[w][32 + r4 + r] = acc2[r];
                    pl[w][48 + r4 + r] = acc3[r];
                }
            }
        }
        __syncthreads();   // bar3: pl L2 ready

        // ---- publish h2[t-1] ----
        if (tid >= 8 && tid < 16 && t >= 1) {
            const int jl = tid - 8;
            float s2[4];
#pragma unroll
            for (int g = 0; g < 4; ++g)
                s2[g] = pl[0][32 + jl * 4 + g] + pl[1][32 + jl * 4 + g]
                      + pl[2][32 + jl * 4 + g] + pl[3][32 + jl * 4 + g];
            const float ig = sigmf(s2[0] + b2g[0]);
            const float fg = sigmf(s2[1] + b2g[1]);
            const float gv = tanhf(s2[2] + b2g[2]);
            const float og = sigmf(s2[3] + b2g[3]);
            c2 = fg * c2 + ig * gv;
            const float h2n = og * tanhf(c2);
            const int s = t - 1;
            const uint pv = (((uint)s & 0xffffu) << 16) | (uint)f2bf(h2n);
            __hip_atomic_store(hp2 + (((s & 1) * 256 + b) << 4) + jl, pv,
                               __ATOMIC_RELAXED, __HIP_MEMORY_SCOPE_AGENT);
        }

        // ---- prefetch next-front h1[t] (verified at top of iter t+1) ----
        if (t < T_) {
            const uint* pn = hp1 + (((t & 1) * 256 + tid) << 4);
#pragma unroll
            for (int i = 0; i < 8; ++i)
                g0n[i] = __hip_atomic_load(pn + i, __ATOMIC_RELAXED, __HIP_MEMORY_SCOPE_AGENT);
        }
    }

    // ---- linear head on h2[T-1] (slot (T-1)&1, tag T-1) : blocks 0..15 ----
    if (b < 16) {
        __syncthreads();
        {
            uint gg[8];
            const uint* p = hp2 + (((((T_ - 1) & 1)) * 256 + tid) << 4);
            poll8(p, (uint)(T_ - 1) & 0xffffu, gg);
            pack_hc(gg, hc + tid * 8);
        }
        __syncthreads();
#pragma unroll
        for (int rr = 0; rr < 2; ++rr) {
            const int r = b * 8 + w * 2 + rr;
            const float* wrow = Wlin + (size_t)r * H_;
            float a = 0.f;
#pragma unroll
            for (int p4 = 0; p4 < 4; ++p4) {
                const int o8 = p4 * 512 + lane * 8;
                const uint4 hq = *(const uint4*)(hc + o8);
                float hv[8];
                hv[0] = __uint_as_float(hq.x << 16); hv[1] = __uint_as_float(hq.x & 0xffff0000u);
                hv[2] = __uint_as_float(hq.y << 16); hv[3] = __uint_as_float(hq.y & 0xffff0000u);
                hv[4] = __uint_as_float(hq.z << 16); hv[5] = __uint_as_float(hq.z & 0xffff0000u);
                hv[6] = __uint_as_float(hq.w << 16); hv[7] = __uint_as_float(hq.w & 0xffff0000u);
                const float4 w0 = *(const float4*)(wrow + o8);
                const float4 w1v = *(const float4*)(wrow + o8 + 4);
                a = fmaf(w0.x, hv[0], a); a = fmaf(w0.y, hv[1], a);
                a = fmaf(w0.z, hv[2], a); a = fmaf(w0.w, hv[3], a);
                a = fmaf(w1v.x, hv[4], a); a = fmaf(w1v.y, hv[5], a);
                a = fmaf(w1v.z, hv[6], a); a = fmaf(w1v.w, hv[7], a);
            }
#pragma unroll
            for (int off = 1; off < 64; off <<= 1) a += __shfl_xor(a, off);
            if (lane == 0) out[r] = a + blin[r];
        }
    }
}

extern "C" void kernel_launch(void* const* d_in, const int* in_sizes, int n_in,
                              void* d_out, int out_size, void* d_ws, size_t ws_size,
                              hipStream_t stream) {
    const float* x    = (const float*)d_in[0];
    const float* Wih1 = (const float*)d_in[1];
    const float* Whh1 = (const float*)d_in[2];
    const float* bih1 = (const float*)d_in[3];
    const float* bhh1 = (const float*)d_in[4];
    const float* Wih2 = (const float*)d_in[5];
    const float* Whh2 = (const float*)d_in[6];
    const float* bih2 = (const float*)d_in[7];
    const float* bhh2 = (const float*)d_in[8];
    const float* Wlin = (const float*)d_in[9];
    const float* blin = (const float*)d_in[10];
    float* out = (float*)d_out;

    // ws layout (bytes):
    // [0, 33554432)          X1   [1024][8192] f32
    // [33554432, 35651584)   x_bf16 [1024][1024]
    // [35651584, 52428800)   W1i_bf16 [8192][1024]
    // [52428800, 52461568)   hp1  [2][256][16] u32 (tagged h1 lines)
    // [52461568, 52494336)   hp2  [2][256][16] u32 (tagged h2 lines)
    float*  X1    = (float*)d_ws;
    ushort* xbf   = (ushort*)((char*)d_ws + 33554432);
    ushort* w1ibf = (ushort*)((char*)d_ws + 35651584);
    uint*   hp1   = (uint*)((char*)d_ws + 52428800);
    uint*   hp2   = (uint*)((char*)d_ws + 52461568);

    hipLaunchKernelGGL(cvt_bf16, dim3(512), dim3(256), 0, stream, x, xbf, 262144);
    hipLaunchKernelGGL(cvt_bf16, dim3(2048), dim3(256), 0, stream, Wih1, w1ibf, 2097152);
    hipLaunchKernelGGL(gemm_x1, dim3(16, 128), dim3(256), 0, stream,
                       (const ushort*)xbf, (const ushort*)w1ibf, bih1, bhh1, X1);
    hipMemsetAsync((void*)hp1, 0xFF, 65536, stream);   // hp1+hp2: invalid tags

    hipLaunchKernelGGL(lstm_mfma, dim3(NBLK), dim3(THR), 0, stream,
                       X1, Whh1, Wih2, Whh2, bih2, bhh2, Wlin, blin,
                       hp1, hp2, out);
}

// Round 18
// 4824.830 us; speedup vs baseline: 1.5681x; 1.5681x over previous
//
#include <hip/hip_runtime.h>

#define T_ 1024
#define S_ 1024
#define H_ 2048
#define A_ 128
#define NBLK 256
#define THR 256

typedef __attribute__((ext_vector_type(8))) short short8;
typedef __attribute__((ext_vector_type(4))) float f32x4;

__device__ __forceinline__ float sigmf(float v) { return 1.0f / (1.0f + __expf(-v)); }

__device__ __forceinline__ ushort f2bf(float f) {
    uint u = __float_as_uint(f);
    return (ushort)((u + 0x7fffu + ((u >> 16) & 1u)) >> 16);
}

__device__ __forceinline__ short8 pack8(const float* __restrict__ s) {
    const float4 f0 = *(const float4*)(s);
    const float4 f1 = *(const float4*)(s + 4);
    uint4 o;
    o.x = (uint)f2bf(f0.x) | ((uint)f2bf(f0.y) << 16);
    o.y = (uint)f2bf(f0.z) | ((uint)f2bf(f0.w) << 16);
    o.z = (uint)f2bf(f1.x) | ((uint)f2bf(f1.y) << 16);
    o.w = (uint)f2bf(f1.z) | ((uint)f2bf(f1.w) << 16);
    return __builtin_bit_cast(short8, o);
}

// verify preloaded tags; on mismatch, re-poll until all carry `tag`
__device__ __forceinline__ void verify8(const uint* __restrict__ p, uint tag, uint* g) {
    for (;;) {
        uint bad = 0;
#pragma unroll
        for (int i = 0; i < 8; ++i) bad |= (g[i] >> 16) ^ tag;
        if (bad == 0) return;
        __builtin_amdgcn_s_sleep(1);
#pragma unroll
        for (int i = 0; i < 8; ++i)
            g[i] = __hip_atomic_load(p + i, __ATOMIC_RELAXED, __HIP_MEMORY_SCOPE_AGENT);
    }
}

__device__ __forceinline__ void poll8(const uint* __restrict__ p, uint tag, uint* g) {
#pragma unroll
    for (int i = 0; i < 8; ++i)
        g[i] = __hip_atomic_load(p + i, __ATOMIC_RELAXED, __HIP_MEMORY_SCOPE_AGENT);
    verify8(p, tag, g);
}

__device__ __forceinline__ void pack_hc(const uint* g, ushort* dst) {
    uint4 o;
    o.x = (g[0] & 0xffffu) | (g[1] << 16); o.y = (g[2] & 0xffffu) | (g[3] << 16);
    o.z = (g[4] & 0xffffu) | (g[5] << 16); o.w = (g[6] & 0xffffu) | (g[7] << 16);
    *(uint4*)dst = o;
}

// ---------------- fp32 -> bf16 (RNE) packed conversion ----------------
__global__ void cvt_bf16(const float* __restrict__ src,
                         ushort* __restrict__ dst, int n4) {
    int i = blockIdx.x * blockDim.x + threadIdx.x;
    const int stride = gridDim.x * blockDim.x;
    for (; i < n4; i += stride) {
        const uint4 u = reinterpret_cast<const uint4*>(src)[i];
        ushort4 o;
        uint a;
        a = u.x; o.x = (ushort)((a + 0x7fffu + ((a >> 16) & 1u)) >> 16);
        a = u.y; o.y = (ushort)((a + 0x7fffu + ((a >> 16) & 1u)) >> 16);
        a = u.z; o.z = (ushort)((a + 0x7fffu + ((a >> 16) & 1u)) >> 16);
        a = u.w; o.w = (ushort)((a + 0x7fffu + ((a >> 16) & 1u)) >> 16);
        reinterpret_cast<ushort4*>(dst)[i] = o;
    }
}

// ---------------- X1 = x @ W_ih1^T + (b_ih1+b_hh1) : MFMA bf16 GEMM ----------------
__global__ __launch_bounds__(256, 2) void gemm_x1(
    const ushort* __restrict__ Abf, const ushort* __restrict__ Bbf,
    const float* __restrict__ bih1, const float* __restrict__ bhh1,
    float* __restrict__ X1) {
    __shared__ ushort At[64][80];
    __shared__ ushort Bt[64][80];
    const int tx = threadIdx.x;
    const int w = tx >> 6, lane = tx & 63;
    const int row0 = blockIdx.x * 64;
    const int col0 = blockIdx.y * 64;
    f32x4 acc[4];
#pragma unroll
    for (int n4 = 0; n4 < 4; ++n4) { acc[n4][0] = 0.f; acc[n4][1] = 0.f; acc[n4][2] = 0.f; acc[n4][3] = 0.f; }
    const int sr = tx >> 2, sc = (tx & 3) * 16;
    for (int k0 = 0; k0 < 1024; k0 += 64) {
        const uint4 a0 = *(const uint4*)(Abf + (size_t)(row0 + sr) * 1024 + k0 + sc);
        const uint4 a1 = *(const uint4*)(Abf + (size_t)(row0 + sr) * 1024 + k0 + sc + 8);
        const uint4 b0 = *(const uint4*)(Bbf + (size_t)(col0 + sr) * 1024 + k0 + sc);
        const uint4 b1 = *(const uint4*)(Bbf + (size_t)(col0 + sr) * 1024 + k0 + sc + 8);
        __syncthreads();
        *(uint4*)(&At[sr][sc]) = a0;
        *(uint4*)(&At[sr][sc + 8]) = a1;
        *(uint4*)(&Bt[sr][sc]) = b0;
        *(uint4*)(&Bt[sr][sc + 8]) = b1;
        __syncthreads();
#pragma unroll
        for (int kk = 0; kk < 64; kk += 32) {
            short8 af = *(const short8*)(&At[16 * w + (lane & 15)][kk + (lane >> 4) * 8]);
#pragma unroll
            for (int n4 = 0; n4 < 4; ++n4) {
                short8 bf = *(const short8*)(&Bt[n4 * 16 + (lane & 15)][kk + (lane >> 4) * 8]);
                acc[n4] = __builtin_amdgcn_mfma_f32_16x16x32_bf16(af, bf, acc[n4], 0, 0, 0);
            }
        }
    }
#pragma unroll
    for (int n4 = 0; n4 < 4; ++n4) {
        const int col = col0 + n4 * 16 + (lane & 15);
        const float bias = bih1[col] + bhh1[col];
#pragma unroll
        for (int r = 0; r < 4; ++r) {
            const int rowv = row0 + 16 * w + (lane >> 4) * 4 + r;
            X1[(size_t)rowv * 8192 + col] = acc[n4][r] + bias;
        }
    }
}

// ---------------- persistent LSTM: pipelined polls, AGPR-resident weights --------
// hp1/hp2: [2][256][16] u32 per-block 64B single-writer tagged lines.
// R16 skeleton (best measured: 4.854 ms):
//  - verify prefetched h1[t-1] -> own-wave stage (no barrier; same-wave ds order)
//  - L1 MFMA; h2[t-2] loads issued after front verify, verified after L1
//    (issue order matters: earlier-issued loads would serialize the verify
//     spin's waitcnt drains -- R17 lesson)
//  - bar2 -> publish h1[t] mid-iter + L2 MFMA -> bar3 -> publish h2[t-1]
//  - prefetch next h1 across the loop-back edge.
__global__ __launch_bounds__(THR, 1) void lstm_mfma(
    const float* __restrict__ X1,
    const float* __restrict__ Whh1,
    const float* __restrict__ W2i, const float* __restrict__ W2h,
    const float* __restrict__ bih2, const float* __restrict__ bhh2,
    const float* __restrict__ Wlin, const float* __restrict__ blin,
    uint* __restrict__ hp1, uint* __restrict__ hp2,
    float* __restrict__ out)
{
    __shared__ ushort hc[4096];    // h1[t-1] (2048) || h2[t-2] (2048) bf16
    __shared__ float pl[4][64];    // per-wave K-partials (rows 0-31 L1, 32-63 L2)

    const int b = blockIdx.x, tid = threadIdx.x;
    const int w = tid >> 6, lane = tid & 63;
    const int j0 = b * 8;
    const int m = lane & 15;
    const int ko = (lane >> 4) * 8;

    // ---- prologue: weight fragments (MFMA A layout), fp32 -> bf16 ----
    short8 a1[2][16];
#pragma unroll
    for (int g = 0; g < 2; ++g) {
        const int r = g * 16 + m;
        const int R = (r & 3) * H_ + j0 + (r >> 2);
        const float* src = Whh1 + (size_t)R * H_ + w * 512 + ko;
#pragma unroll
        for (int c = 0; c < 16; ++c)
            a1[g][c] = pack8(src + c * 32);
    }
    short8 a2[2][32];
#pragma unroll
    for (int g = 0; g < 2; ++g) {
        const int r = g * 16 + m;
        const int R = (r & 3) * H_ + j0 + (r >> 2);
        const float* base = (w < 2) ? (W2i + (size_t)R * H_ + w * 1024 + ko)
                                    : (W2h + (size_t)R * H_ + (w - 2) * 1024 + ko);
#pragma unroll
        for (int c = 0; c < 32; ++c)
            a2[g][c] = pack8(base + c * 32);
    }

    float c1 = 0.f, c2 = 0.f;
    float b2g[4] = {0.f, 0.f, 0.f, 0.f};
    if (tid >= 8 && tid < 16) {
        const int jl = tid - 8;
#pragma unroll
        for (int g = 0; g < 4; ++g) {
            const int R = g * H_ + j0 + jl;
            b2g[g] = bih2[R] + bhh2[R];
        }
    }

    uint g0n[8];   // prefetched h1 line (carried across iterations)
#pragma unroll
    for (int i = 0; i < 8; ++i) g0n[i] = 0u;

#pragma unroll 1
    for (int t = 0; t <= T_; ++t) {
        // early per-thread X1 fetch (threads 0..7)
        float xg[4] = {0.f, 0.f, 0.f, 0.f};
        if (tid < 8 && t < T_) {
#pragma unroll
            for (int g = 0; g < 4; ++g)
                xg[g] = X1[(size_t)t * 8192 + g * H_ + j0 + tid];
        }

        // ---- FRONT: verify prefetched h1[t-1] (round hidden under loop-back) ----
        if (t >= 1) {
            const uint* p = hp1 + ((((t - 1) & 1) * 256 + tid) << 4);
            verify8(p, (uint)(t - 1) & 0xffffu, g0n);
        }
        pack_hc(g0n, hc + tid * 8);   // t==0: zeros; own-wave slice of the front half

        // ---- issue BACK loads h2[t-2] now; verify after L1 MFMA ----
        uint g1[8];
        if (t >= 2) {
            const uint* p2 = hp2 + ((((t - 2) & 1) * 256 + tid) << 4);
#pragma unroll
            for (int i = 0; i < 8; ++i)
                g1[i] = __hip_atomic_load(p2 + i, __ATOMIC_RELAXED, __HIP_MEMORY_SCOPE_AGENT);
        } else {
#pragma unroll
            for (int i = 0; i < 8; ++i) g1[i] = 0u;
        }
        // (bar1 removed: L1 below reads only this wave's own staged slice)

        // ---- L1 MFMA over h1[t-1] (own-wave slice) ----
        if (t < T_) {
            f32x4 acc0, acc1;
#pragma unroll
            for (int r = 0; r < 4; ++r) { acc0[r] = 0.f; acc1[r] = 0.f; }
            const ushort* h1s = hc + w * 512;
#pragma unroll
            for (int c = 0; c < 16; ++c) {
                const short8 bfr = *(const short8*)(h1s + c * 32 + ko);
                acc0 = __builtin_amdgcn_mfma_f32_16x16x32_bf16(a1[0][c], bfr, acc0, 0, 0, 0);
                acc1 = __builtin_amdgcn_mfma_f32_16x16x32_bf16(a1[1][c], bfr, acc1, 0, 0, 0);
            }
            if (m == 0) {
                const int r4 = (lane >> 4) * 4;
#pragma unroll
                for (int r = 0; r < 4; ++r) {
                    pl[w][ 0 + r4 + r] = acc0[r];
                    pl[w][16 + r4 + r] = acc1[r];
                }
            }
        }

        // ---- BACK verify (L3 round hidden under L1 MFMA) + stage h2[t-2] ----
        if (t >= 2) {
            const uint* p2 = hp2 + ((((t - 2) & 1) * 256 + tid) << 4);
            verify8(p2, (uint)(t - 2) & 0xffffu, g1);
        }
        pack_hc(g1, hc + 2048 + tid * 8);   // disjoint from L1's hc reads
        __syncthreads();   // bar2: pl L1 + all staging (front+back) ready

        // ---- publish h1[t] (mid-iter) ----
        if (tid < 8 && t < T_) {
            float s[4];
#pragma unroll
            for (int g = 0; g < 4; ++g)
                s[g] = pl[0][tid * 4 + g] + pl[1][tid * 4 + g]
                     + pl[2][tid * 4 + g] + pl[3][tid * 4 + g];
            const float ig = sigmf(s[0] + xg[0]);
            const float fg = sigmf(s[1] + xg[1]);
            const float gv = tanhf(s[2] + xg[2]);
            const float og = sigmf(s[3] + xg[3]);
            c1 = fg * c1 + ig * gv;
            const float h1n = og * tanhf(c1);
            const uint pv = (((uint)t & 0xffffu) << 16) | (uint)f2bf(h1n);
            __hip_atomic_store(hp1 + (((t & 1) * 256 + b) << 4) + tid, pv,
                               __ATOMIC_RELAXED, __HIP_MEMORY_SCOPE_AGENT);
        }

        // ---- L2 MFMA over [h1[t-1]; h2[t-2]] ----
        if (t >= 1) {
            f32x4 acc2, acc3;
#pragma unroll
            for (int r = 0; r < 4; ++r) { acc2[r] = 0.f; acc3[r] = 0.f; }
            const ushort* hcs = hc + w * 1024;
#pragma unroll
            for (int c = 0; c < 32; ++c) {
                const short8 bfr = *(const short8*)(hcs + c * 32 + ko);
                acc2 = __builtin_amdgcn_mfma_f32_16x16x32_bf16(a2[0][c], bfr, acc2, 0, 0, 0);
                acc3 = __builtin_amdgcn_mfma_f32_16x16x32_bf16(a2[1][c], bfr, acc3, 0, 0, 0);
            }
            if (m == 0) {
                const int r4 = (lane >> 4) * 4;
#pragma unroll
                for (int r = 0; r < 4; ++r) {
                    pl[w][32 + r4 + r] = acc2[r];
                    pl[w][48 + r4 + r] = acc3[r];
                }
            }
        }
        __syncthreads();   // bar3: pl L2 ready

        // ---- publish h2[t-1] ----
        if (tid >= 8 && tid < 16 && t >= 1) {
            const int jl = tid - 8;
            float s2[4];
#pragma unroll
            for (int g = 0; g < 4; ++g)
                s2[g] = pl[0][32 + jl * 4 + g] + pl[1][32 + jl * 4 + g]
                      + pl[2][32 + jl * 4 + g] + pl[3][32 + jl * 4 + g];
            const float ig = sigmf(s2[0] + b2g[0]);
            const float fg = sigmf(s2[1] + b2g[1]);
            const float gv = tanhf(s2[2] + b2g[2]);
            const float og = sigmf(s2[3] + b2g[3]);
            c2 = fg * c2 + ig * gv;
            const float h2n = og * tanhf(c2);
            const int s = t - 1;
            const uint pv = (((uint)s & 0xffffu) << 16) | (uint)f2bf(h2n);
            __hip_atomic_store(hp2 + (((s & 1) * 256 + b) << 4) + jl, pv,
                               __ATOMIC_RELAXED, __HIP_MEMORY_SCOPE_AGENT);
        }

        // ---- prefetch next-front h1[t] (verified at top of iter t+1) ----
        if (t < T_) {
            const uint* pn = hp1 + (((t & 1) * 256 + tid) << 4);
#pragma unroll
            for (int i = 0; i < 8; ++i)
                g0n[i] = __hip_atomic_load(pn + i, __ATOMIC_RELAXED, __HIP_MEMORY_SCOPE_AGENT);
        }
    }

    // ---- linear head on h2[T-1] (slot (T-1)&1, tag T-1) : blocks 0..15 ----
    if (b < 16) {
        __syncthreads();
        {
            uint gg[8];
            const uint* p = hp2 + (((((T_ - 1) & 1)) * 256 + tid) << 4);
            poll8(p, (uint)(T_ - 1) & 0xffffu, gg);
            pack_hc(gg, hc + tid * 8);
        }
        __syncthreads();
#pragma unroll
        for (int rr = 0; rr < 2; ++rr) {
            const int r = b * 8 + w * 2 + rr;
            const float* wrow = Wlin + (size_t)r * H_;
            float a = 0.f;
#pragma unroll
            for (int p4 = 0; p4 < 4; ++p4) {
                const int o8 = p4 * 512 + lane * 8;
                const uint4 hq = *(const uint4*)(hc + o8);
                float hv[8];
                hv[0] = __uint_as_float(hq.x << 16); hv[1] = __uint_as_float(hq.x & 0xffff0000u);
                hv[2] = __uint_as_float(hq.y << 16); hv[3] = __uint_as_float(hq.y & 0xffff0000u);
                hv[4] = __uint_as_float(hq.z << 16); hv[5] = __uint_as_float(hq.z & 0xffff0000u);
                hv[6] = __uint_as_float(hq.w << 16); hv[7] = __uint_as_float(hq.w & 0xffff0000u);
                const float4 w0 = *(const float4*)(wrow + o8);
                const float4 w1v = *(const float4*)(wrow + o8 + 4);
                a = fmaf(w0.x, hv[0], a); a = fmaf(w0.y, hv[1], a);
                a = fmaf(w0.z, hv[2], a); a = fmaf(w0.w, hv[3], a);
                a = fmaf(w1v.x, hv[4], a); a = fmaf(w1v.y, hv[5], a);
                a = fmaf(w1v.z, hv[6], a); a = fmaf(w1v.w, hv[7], a);
            }
#pragma unroll
            for (int off = 1; off < 64; off <<= 1) a += __shfl_xor(a, off);
            if (lane == 0) out[r] = a + blin[r];
        }
    }
}

extern "C" void kernel_launch(void* const* d_in, const int* in_sizes, int n_in,
                              void* d_out, int out_size, void* d_ws, size_t ws_size,
                              hipStream_t stream) {
    const float* x    = (const float*)d_in[0];
    const float* Wih1 = (const float*)d_in[1];
    const float* Whh1 = (const float*)d_in[2];
    const float* bih1 = (const float*)d_in[3];
    const float* bhh1 = (const float*)d_in[4];
    const float* Wih2 = (const float*)d_in[5];
    const float* Whh2 = (const float*)d_in[6];
    const float* bih2 = (const float*)d_in[7];
    const float* bhh2 = (const float*)d_in[8];
    const float* Wlin = (const float*)d_in[9];
    const float* blin = (const float*)d_in[10];
    float* out = (float*)d_out;

    // ws layout (bytes):
    // [0, 33554432)          X1   [1024][8192] f32
    // [33554432, 35651584)   x_bf16 [1024][1024]
    // [35651584, 52428800)   W1i_bf16 [8192][1024]
    // [52428800, 52461568)   hp1  [2][256][16] u32 (tagged h1 lines)
    // [52461568, 52494336)   hp2  [2][256][16] u32 (tagged h2 lines)
    float*  X1    = (float*)d_ws;
    ushort* xbf   = (ushort*)((char*)d_ws + 33554432);
    ushort* w1ibf = (ushort*)((char*)d_ws + 35651584);
    uint*   hp1   = (uint*)((char*)d_ws + 52428800);
    uint*   hp2   = (uint*)((char*)d_ws + 52461568);

    hipLaunchKernelGGL(cvt_bf16, dim3(512), dim3(256), 0, stream, x, xbf, 262144);
    hipLaunchKernelGGL(cvt_bf16, dim3(2048), dim3(256), 0, stream, Wih1, w1ibf, 2097152);
    hipLaunchKernelGGL(gemm_x1, dim3(16, 128), dim3(256), 0, stream,
                       (const ushort*)xbf, (const ushort*)w1ibf, bih1, bhh1, X1);
    hipMemsetAsync((void*)hp1, 0xFF, 65536, stream);   // hp1+hp2: invalid tags

    hipLaunchKernelGGL(lstm_mfma, dim3(NBLK), dim3(THR), 0, stream,
                       X1, Whh1, Wih2, Whh2, bih2, bhh2, Wlin, blin,
                       hp1, hp2, out);
}